// Round 8
// baseline (41.413 us; speedup 1.0000x reference)
//
#include <hip/hip_runtime.h>
#include <hip/hip_bf16.h>

#define NEG_SLOPE 0.2f

typedef float f32x4 __attribute__((ext_vector_type(4)));

// bf16 helpers (RTN-even pack, shift-unpack)
__device__ __forceinline__ unsigned f2bf(float f) {
    unsigned u = __float_as_uint(f);
    return (u + 0x7FFFu + ((u >> 16) & 1u)) >> 16;
}
__device__ __forceinline__ float bf2f(unsigned h) {
    return __uint_as_float(h << 16);
}

// ---------------------------------------------------------------------------
// Kernel A: v = W^T a folds (tiny, 1 block). v layout: [4][128].
// ---------------------------------------------------------------------------
__global__ void compute_v_kernel(const float* __restrict__ W_b,
                                 const float* __restrict__ W_p,
                                 const float* __restrict__ a_b,
                                 const float* __restrict__ a_p,
                                 float* __restrict__ v) {
    const int t  = threadIdx.x;          // 0..255
    const int p  = t & 127;
    const int ch = t >> 7;               // 0 = behavior, 1 = preference
    const float* W = ch ? W_p : W_b;
    const float* a = ch ? a_p : a_b;
    float acc1 = 0.f, acc2 = 0.f;
    #pragma unroll
    for (int d = 0; d < 64; ++d) {
        const float w = W[d * 128 + p];
        acc1 += w * a[d];
        acc2 += w * a[64 + d];
    }
    v[(2 * ch + 0) * 128 + p] = acc1;
    v[(2 * ch + 1) * 128 + p] = acc2;
}

// ---------------------------------------------------------------------------
// Folded 64-lane reduction (6 shuffles) — see R5.
// ---------------------------------------------------------------------------
__device__ __forceinline__ float fold_reduce(float sib, float sjb,
                                             float sip, float sjp,
                                             bool hiB, bool hiJ) {
    float g1 = hiB ? sib : sip;
    float r1 = __shfl_xor(g1, 16);
    float acc_i = (hiB ? sip : sib) + r1;
    float g2 = hiB ? sjb : sjp;
    float r2 = __shfl_xor(g2, 16);
    float acc_j = (hiB ? sjp : sjb) + r2;
    float g3 = hiJ ? acc_i : acc_j;
    float r3 = __shfl_xor(g3, 8);
    float acc = (hiJ ? acc_j : acc_i) + r3;
    acc += __shfl_xor(acc, 4);
    acc += __shfl_xor(acc, 2);
    acc += __shfl_xor(acc, 1);
    return acc;
}

__device__ __forceinline__ float dot4(const f32x4 z, const f32x4 v) {
    return z.x * v.x + z.y * v.y + z.z * v.z + z.w * v.w;
}

// Funnel the 4 components to lane c==0, pack 4xbf16 into uint2, 8 B store.
__device__ __forceinline__ void pack_store(float acc, int c, bool valid,
                                           uint2* __restrict__ tab8, int node) {
    const float a1 = __shfl_down(acc, 8);
    const float a2 = __shfl_down(acc, 16);
    const float a3 = __shfl_down(acc, 24);
    if (c == 0 && valid) {
        uint2 p;
        p.x = f2bf(acc) | (f2bf(a1) << 16);
        p.y = f2bf(a2) | (f2bf(a3) << 16);
        tab8[node] = p;
    }
}

// ---------------------------------------------------------------------------
// Node kernel — m13 streaming shape: 2048x256, no LDS/barriers, 8 blocks/CU
// (32 waves/CU), VGPR pinned <=64 via launch_bounds. 4-pair unroll: all 8
// f32x4 loads (128 B/lane) issued before any reduction. Load/reduce guards
// depend only on pr (wave-uniform) -> s_cbranch, no divergence.
// ---------------------------------------------------------------------------
__global__ void __launch_bounds__(256, 8) node_scores_kernel(
        const f32x4* __restrict__ zb4,
        const f32x4* __restrict__ zp4,
        const float* __restrict__ v,
        uint2*       __restrict__ tab8,
        int n_nodes) {
    const int tid  = threadIdx.x;
    const int lane = tid & 63;
    const int h    = lane >> 5;                 // which node of the pair
    const int c    = lane & 31;                 // f32x4 column group
    const int wave   = (blockIdx.x * blockDim.x + tid) >> 6;
    const int nwaves = (gridDim.x * blockDim.x) >> 6;   // 8192
    const int npairs = (n_nodes + 1) >> 1;

    const f32x4 v1b = *reinterpret_cast<const f32x4*>(v + 0 * 128 + 4 * c);
    const f32x4 v2b = *reinterpret_cast<const f32x4*>(v + 1 * 128 + 4 * c);
    const f32x4 v1p = *reinterpret_cast<const f32x4*>(v + 2 * 128 + 4 * c);
    const f32x4 v2p = *reinterpret_cast<const f32x4*>(v + 3 * 128 + 4 * c);

    const bool hiB = (c & 16) != 0;
    const bool hiJ = (c & 8)  != 0;

    for (int pr0 = wave; pr0 < npairs; pr0 += 4 * nwaves) {
        f32x4 zb[4], zp[4];
        // phase 1: issue all loads (wave-uniform guards)
        #pragma unroll
        for (int j = 0; j < 4; ++j) {
            const int pr = pr0 + j * nwaves;
            if (pr < npairs) {
                const size_t base = (size_t)(2 * pr + h) * 32 + c;
                zb[j] = zb4[base];
                zp[j] = zp4[base];
            }
        }
        // phase 2: reduce + store
        #pragma unroll
        for (int j = 0; j < 4; ++j) {
            const int pr = pr0 + j * nwaves;
            if (pr < npairs) {
                const int node = 2 * pr + h;
                const float acc = fold_reduce(
                    dot4(zb[j], v1b), dot4(zb[j], v2b),
                    dot4(zp[j], v1p), dot4(zp[j], v2p), hiB, hiJ);
                pack_store(acc, c, node < n_nodes, tab8, node);
            }
        }
    }
}

// ---------------------------------------------------------------------------
// Edge kernel — unchanged from R7 (2 edges/thread, 8 B bf16x4 gathers).
// ---------------------------------------------------------------------------
__device__ __forceinline__ float lrelu(float x) {
    return x >= 0.f ? x : NEG_SLOPE * x;
}

__device__ __forceinline__ float edge_score8(const uint2 ts, const uint2 td,
                                             float w0, float w1) {
    const float s_ib = bf2f(ts.x & 0xFFFFu), s_jb = bf2f(ts.x >> 16);
    const float s_ip = bf2f(ts.y & 0xFFFFu), s_jp = bf2f(ts.y >> 16);
    const float d_ib = bf2f(td.x & 0xFFFFu), d_jb = bf2f(td.x >> 16);
    const float d_ip = bf2f(td.y & 0xFFFFu), d_jp = bf2f(td.y >> 16);
    const float sb = 0.5f * (lrelu(s_ib + d_jb) + lrelu(d_ib + s_jb));
    const float sp = 0.5f * (lrelu(s_ip + d_jp) + lrelu(d_ip + s_jp));
    const float sc = w0 * sb + w1 * sp;            // TAU_MRF == 1
    return 1.f / (1.f + __expf(-sc));
}

__global__ void __launch_bounds__(256) edge_scores_kernel(
        const int*   __restrict__ src,
        const int*   __restrict__ dst,
        const uint2* __restrict__ tab8,
        const float* __restrict__ gamma_b,
        const float* __restrict__ gamma_p,
        float*       __restrict__ out,
        int n_edges) {
    const float gb = *gamma_b;
    const float gp = *gamma_p;
    const float w0 = 1.f / (1.f + __expf(gp - gb));  // softmax over 2 logits
    const float w1 = 1.f - w0;

    const int n_half = n_edges >> 1;
    const int stride = gridDim.x * blockDim.x;
    const int gid    = blockIdx.x * blockDim.x + threadIdx.x;

    const int2* src2 = (const int2*)src;
    const int2* dst2 = (const int2*)dst;
    float2*     out2 = (float2*)out;

    for (int i = gid; i < n_half; i += stride) {
        const int2 s = src2[i];
        const int2 d = dst2[i];
        const uint2 ts0 = tab8[s.x];
        const uint2 td0 = tab8[d.x];
        const uint2 ts1 = tab8[s.y];
        const uint2 td1 = tab8[d.y];
        float2 r;
        r.x = edge_score8(ts0, td0, w0, w1);
        r.y = edge_score8(ts1, td1, w0, w1);
        out2[i] = r;
    }
    const int tail_base = n_half << 1;
    for (int e = tail_base + gid; e < n_edges; e += stride) {
        out[e] = edge_score8(tab8[src[e]], tab8[dst[e]], w0, w1);
    }
}

extern "C" void kernel_launch(void* const* d_in, const int* in_sizes, int n_in,
                              void* d_out, int out_size, void* d_ws, size_t ws_size,
                              hipStream_t stream) {
    const float* z_beh  = (const float*)d_in[0];
    const float* z_pref = (const float*)d_in[1];
    const float* W_b    = (const float*)d_in[2];
    const float* W_p    = (const float*)d_in[3];
    const float* a_b    = (const float*)d_in[4];
    const float* a_p    = (const float*)d_in[5];
    const float* g_b    = (const float*)d_in[6];
    const float* g_p    = (const float*)d_in[7];
    const int*   ei     = (const int*)d_in[8];   // [2, E] int32

    const int n_nodes = in_sizes[0] / 128;
    const int n_edges = in_sizes[8] / 2;

    float* v    = (float*)d_ws;                          // 512 floats
    uint2* tab8 = (uint2*)((char*)d_ws + 2048);          // n_nodes * 8 B

    compute_v_kernel<<<1, 256, 0, stream>>>(W_b, W_p, a_b, a_p, v);

    // m13 shape: 2048 x 256 = 8192 waves, 8 blocks/CU, full occupancy
    node_scores_kernel<<<2048, 256, 0, stream>>>(
        (const f32x4*)z_beh, (const f32x4*)z_pref, v, tab8, n_nodes);

    const int n_half = n_edges >> 1;
    int eblocks = (n_half + 255) / 256;
    if (eblocks > 4096) eblocks = 4096;
    if (eblocks < 1) eblocks = 1;
    edge_scores_kernel<<<eblocks, 256, 0, stream>>>(
        ei, ei + n_edges, tab8, g_b, g_p, (float*)d_out, n_edges);
}